// Round 15
// baseline (492.775 us; speedup 1.0000x reference)
//
#include <hip/hip_runtime.h>
#include <hip/hip_bf16.h>
#include <cstdint>

// Problem shapes (fixed)
#define B_     2
#define N_     2048
#define DIM_   1024
#define H_     16
#define DH_    64
#define MEM_   2048
#define JT_    4096      // MEM_ + N_
#define INNER_ 1024
#define SCALE_ 0.125f

typedef float f32x4 __attribute__((ext_vector_type(4)));
typedef short s16x8 __attribute__((ext_vector_type(8)));
typedef short s16x4 __attribute__((ext_vector_type(4)));

__device__ __forceinline__ short bf16_of(float f) {
    __hip_bfloat16 h = __float2bfloat16(f);   // RNE
    return *(short*)&h;
}

__device__ __forceinline__ void gload16(const void* g, short* l) {
    __builtin_amdgcn_global_load_lds(
        (const __attribute__((address_space(1))) unsigned int*)g,
        (__attribute__((address_space(3))) unsigned int*)l, 16, 0, 0);
}

// ---------------------------------------------------------------------------
// Kernel A: cast x fp32 [4096][1024] -> xb bf16 (row-major)
// ---------------------------------------------------------------------------
__global__ __launch_bounds__(256) void cast_x(
    const float* __restrict__ x, short* __restrict__ xb)
{
    const int total4 = B_ * N_ * DIM_ / 4;   // 1M
    for (int idx = blockIdx.x * blockDim.x + threadIdx.x; idx < total4;
         idx += gridDim.x * blockDim.x) {
        float4 v = ((const float4*)x)[idx];
        s16x4 o;
        o[0] = bf16_of(v.x); o[1] = bf16_of(v.y);
        o[2] = bf16_of(v.z); o[3] = bf16_of(v.w);
        *(s16x4*)&xb[idx * 4] = o;
    }
}

// ---------------------------------------------------------------------------
// Kernel B: transpose-cast weights -> Wt bf16 [3072][1024], Wt[n][k]=W[k][n].
// SCALE folded into q columns (n<1024).
// ---------------------------------------------------------------------------
__global__ __launch_bounds__(256) void cast_w(
    const float* __restrict__ Wq, const float* __restrict__ Wkv,
    short* __restrict__ Wt)
{
    const int kt = blockIdx.x;   // 0..15
    const int nt = blockIdx.y;   // 0..47
    __shared__ float tile[64][65];   // [n_local][k_local]
    const int t = threadIdx.x;
    const int r = t >> 2, s4 = (t & 3) * 16;

    const int n0 = nt * 64;
    const float* src;
    int ldn, nc0;
    if (n0 < 1024) { src = Wq;  ldn = 1024; nc0 = n0; }
    else           { src = Wkv; ldn = 2048; nc0 = n0 - 1024; }
    const float scale = (n0 < 1024) ? SCALE_ : 1.0f;

#pragma unroll
    for (int kq = 0; kq < 4; ++kq) {
        float4 v = *(const float4*)&src[(size_t)(kt * 64 + r) * ldn + nc0 + s4 + kq * 4];
        tile[s4 + kq * 4 + 0][r] = v.x;
        tile[s4 + kq * 4 + 1][r] = v.y;
        tile[s4 + kq * 4 + 2][r] = v.z;
        tile[s4 + kq * 4 + 3][r] = v.w;
    }
    __syncthreads();
    short ov[16];
#pragma unroll
    for (int e = 0; e < 16; ++e) ov[e] = bf16_of(tile[r][s4 + e] * scale);
    short* dst = &Wt[(size_t)(n0 + r) * 1024 + kt * 64 + s4];
    *(s16x8*)&dst[0] = *(s16x8*)&ov[0];
    *(s16x8*)&dst[8] = *(s16x8*)&ov[8];
}

// ---------------------------------------------------------------------------
// Kernel C: MFMA projection GEMM (unchanged from passing rounds 3-14).
// ---------------------------------------------------------------------------
#define PLDC 152

__global__ __launch_bounds__(256) void mfma_proj(
    const short* __restrict__ Wt, const short* __restrict__ xb,
    short* __restrict__ qbuf, short* __restrict__ kbuf, short* __restrict__ vtbuf)
{
    const int bc = blockIdx.x;
    const int bi = blockIdx.y;
    const int tid = threadIdx.x;
    const int w = tid >> 6, lane = tid & 63, g = lane >> 4, li = lane & 15;
    const int wr = w >> 1, wc = w & 1;

    __shared__ short smem[128 * PLDC];
    short* A_lds = smem;
    short* B_lds = smem + 8192;

    f32x4 acc[4][4];
#pragma unroll
    for (int m = 0; m < 4; ++m)
#pragma unroll
        for (int n = 0; n < 4; ++n) acc[m][n] = f32x4{0.f, 0.f, 0.f, 0.f};

    const size_t arow0 = (size_t)bc * 128;
    const size_t brow0 = (size_t)bi * 128;

    for (int t = 0; t < 16; ++t) {
        __syncthreads();
#pragma unroll
        for (int u = 0; u < 4; ++u) {
            const int c = (w * 4 + u) * 64 + lane;
            const int row = c >> 3, q = c & 7;
            const int qs = q ^ (row & 7);
            gload16(&Wt[(arow0 + row) * 1024 + t * 64 + qs * 8],
                    &A_lds[(w * 4 + u) * 512 + lane * 8]);
            gload16(&xb[(brow0 + row) * 1024 + t * 64 + qs * 8],
                    &B_lds[(w * 4 + u) * 512 + lane * 8]);
        }
        __syncthreads();
#pragma unroll
        for (int kc = 0; kc < 2; ++kc) {
            s16x8 af[4], bf[4];
#pragma unroll
            for (int mt = 0; mt < 4; ++mt) {
                const int row = wr * 64 + mt * 16 + li;
                af[mt] = *(const s16x8*)&A_lds[row * 64 + ((kc * 4 + g) ^ (row & 7)) * 8];
            }
#pragma unroll
            for (int nt = 0; nt < 4; ++nt) {
                const int row = wc * 64 + nt * 16 + li;
                bf[nt] = *(const s16x8*)&B_lds[row * 64 + ((kc * 4 + g) ^ (row & 7)) * 8];
            }
#pragma unroll
            for (int mt = 0; mt < 4; ++mt)
#pragma unroll
                for (int nt = 0; nt < 4; ++nt)
                    acc[mt][nt] = __builtin_amdgcn_mfma_f32_16x16x32_bf16(af[mt], bf[nt], acc[mt][nt], 0, 0, 0);
        }
    }

    __syncthreads();
    const int c0 = bc * 128;
    const int i0g = bi * 128;
    const int b = i0g >> 11;
    const int ii0 = i0g & 2047;

    if (c0 < 2048) {
#pragma unroll
        for (int mt = 0; mt < 4; ++mt)
#pragma unroll
            for (int nt = 0; nt < 4; ++nt) {
                const int i_l = wc * 64 + nt * 16 + li;
                const int c_l = wr * 64 + mt * 16 + g * 4;
                s16x4 v4;
                v4[0] = bf16_of(acc[mt][nt][0]);
                v4[1] = bf16_of(acc[mt][nt][1]);
                v4[2] = bf16_of(acc[mt][nt][2]);
                v4[3] = bf16_of(acc[mt][nt][3]);
                *(s16x4*)&smem[i_l * PLDC + c_l] = v4;
            }
        __syncthreads();
        const bool isq = (c0 < 1024);
#pragma unroll
        for (int u = 0; u < 8; ++u) {
            const int ch = tid + u * 256;
            const int i_l = ch >> 4, seg = ch & 15;
            s16x8 v = *(const s16x8*)&smem[i_l * PLDC + seg * 8];
            const int cg = c0 + seg * 8;
            const int h = (cg >> 6) & 15;
            const int d = cg & 63;
            if (isq)
                *(s16x8*)&qbuf[(((size_t)(b * H_ + h)) * N_ + ii0 + i_l) * DH_ + d] = v;
            else
                *(s16x8*)&kbuf[(((size_t)(b * H_ + h)) * JT_ + MEM_ + ii0 + i_l) * DH_ + d] = v;
        }
    } else {
#pragma unroll
        for (int mt = 0; mt < 4; ++mt)
#pragma unroll
            for (int nt = 0; nt < 4; ++nt) {
                const int i_l = wc * 64 + nt * 16 + li;
                const int c_b = wr * 64 + mt * 16 + g * 4;
#pragma unroll
                for (int r = 0; r < 4; ++r)
                    smem[(c_b + r) * PLDC + i_l] = bf16_of(acc[mt][nt][r]);
            }
        __syncthreads();
#pragma unroll
        for (int u = 0; u < 8; ++u) {
            const int ch = tid + u * 256;
            const int c_l = ch >> 4, seg = ch & 15;
            s16x8 v = *(const s16x8*)&smem[c_l * PLDC + seg * 8];
            const int cv = c0 + c_l - 2048;
            const int h = cv >> 6, d = cv & 63;
            *(s16x8*)&vtbuf[(((size_t)(b * H_ + h)) * DH_ + d) * JT_ + MEM_ + ii0 + seg * 8] = v;
        }
    }
}

// ---------------------------------------------------------------------------
// Kernel D (fused): mem_k copy-cast + mem_v transpose-cast, one launch.
// ---------------------------------------------------------------------------
__global__ __launch_bounds__(256) void prep_mem(
    const float* __restrict__ mem_k, const float* __restrict__ mem_v,
    short* __restrict__ kbuf, short* __restrict__ vtbuf)
{
    const int jt = blockIdx.x, h = blockIdx.y;
    const int b = blockIdx.z & 1, task = blockIdx.z >> 1;
    const int j0 = jt * 64;
    const int t = threadIdx.x;
    const int r = t >> 2, s4 = (t & 3) * 16;
    const size_t bh = (size_t)(b * H_ + h);

    if (task == 0) {
        short ov[16];
#pragma unroll
        for (int k = 0; k < 4; ++k) {
            float4 v = *(const float4*)&mem_k[((size_t)(b * MEM_ + j0 + r)) * INNER_ + h * DH_ + s4 + k * 4];
            ov[k * 4 + 0] = bf16_of(v.x);
            ov[k * 4 + 1] = bf16_of(v.y);
            ov[k * 4 + 2] = bf16_of(v.z);
            ov[k * 4 + 3] = bf16_of(v.w);
        }
        short* dst = &kbuf[(bh * JT_ + j0 + r) * DH_ + s4];
        *(s16x8*)&dst[0] = *(s16x8*)&ov[0];
        *(s16x8*)&dst[8] = *(s16x8*)&ov[8];
    } else {
        __shared__ float tile[64][65];
#pragma unroll
        for (int k = 0; k < 4; ++k) {
            float4 v = *(const float4*)&mem_v[((size_t)(b * MEM_ + j0 + r)) * INNER_ + h * DH_ + s4 + k * 4];
            tile[s4 + k * 4 + 0][r] = v.x;
            tile[s4 + k * 4 + 1][r] = v.y;
            tile[s4 + k * 4 + 2][r] = v.z;
            tile[s4 + k * 4 + 3][r] = v.w;
        }
        __syncthreads();
        short ov[16];
#pragma unroll
        for (int e = 0; e < 16; ++e) ov[e] = bf16_of(tile[r][s4 + e]);
        short* dst = &vtbuf[(bh * DH_ + r) * JT_ + j0 + s4];
        *(s16x8*)&dst[0] = *(s16x8*)&ov[0];
        *(s16x8*)&dst[8] = *(s16x8*)&ov[8];
    }
}

// ---------------------------------------------------------------------------
// Kernel F: flash attention v12 — BARRIER-FREE. 1024 blocks x 4 waves x 16q.
//   No K/V LDS, no gload_lds, no __syncthreads: every wave is fully
//   independent. K/V MFMA fragments read directly from global (perfect
//   64B-line utilization: each frag instr = 16 rows x 64B) into loop-carried
//   registers prefetched ONE TILE AHEAD at their consumption points
//   (r9-proven against sinking; window ~ full tile covers L2/HBM latency).
//   LDS = 8KB P only (per-wave, granule-swizzled) -> stalls from barrier
//   drain + rendezvous (the r13 limiter: ~2350cy/wave-tile wall vs ~700cy
//   work) are structurally eliminated. 12 waves/CU (VGPR ~150, bounds
//   (256,3)), 3 independent blocks/CU.
//   Retained: swapped-operand softmax, defer-max THR=8, deferred l-reduce,
//   bias as MFMA C-in prefetched 1 tile ahead, h%8 XCD, zq pairing.
// ---------------------------------------------------------------------------
__global__ __launch_bounds__(256, 3) void attn_flash(
    const short* __restrict__ qbuf, const short* __restrict__ kbuf,
    const short* __restrict__ vtbuf, const float* __restrict__ pos_bias,
    float* __restrict__ out)
{
    const int lid = blockIdx.x;                       // 0..1023
    const int h   = (lid & 7) | (((lid >> 3) & 1) << 3);   // h%8 = XCD
    const int b   = (lid >> 4) & 1;
    const int zql = (lid >> 5) & 15;
    const int hi  = lid >> 9;
    const int zq  = hi ? (31 - zql) : zql;            // balanced pairing
    const int i0  = zq * 64;                          // block's 64-query base

    const int tid = threadIdx.x;
    const int w = tid >> 6, lane = tid & 63, g = lane >> 4, li = lane & 15;

    __shared__ short P_lds[4][16 * 64];    // 8 KB total; per-wave region

    const size_t bh = (size_t)(b * H_ + h);
    const short* kg  = kbuf  + bh * (size_t)JT_ * DH_;
    const short* vtg = vtbuf + bh * (size_t)DH_ * JT_;
    const float* pb  = pos_bias + (size_t)h * N_ * JT_;

    const int qw = i0 + w * 16;            // wave's 16 q-rows

    // Q fragments (B operand of swapped QK^T): lane (g,li) holds Q[qw+li][k]
    s16x8 aq[2];
#pragma unroll
    for (int kc = 0; kc < 2; ++kc)
        aq[kc] = *(const s16x8*)&qbuf[(bh * N_ + qw + li) * DH_ + kc * 32 + g * 8];

    f32x4 o[4];
    float m_run = -3.0e38f, l_run = 0.f;   // l_run: per-lane partial sum
#pragma unroll
    for (int dt = 0; dt < 4; ++dt) o[dt] = f32x4{0.f, 0.f, 0.f, 0.f};

    const int ntiles = 33 + zq;   // covers j <= 2048 + i0 + 63

    // ---- loop-carried prefetch registers (r9-proven pattern) ----
    s16x8 kf[2][4];               // K frags  [kc][nt]: row j = j0+nt*16+li
    s16x8 vf[2][4];               // V^T frags [kc][dt]: row d = dt*16+li
    f32x4 bnext[4];               // bias

    #define LOADK(j0s)                                                         \
    {                                                                          \
        _Pragma("unroll")                                                      \
        for (int kc = 0; kc < 2; ++kc)                                         \
        _Pragma("unroll")                                                      \
        for (int nt = 0; nt < 4; ++nt)                                         \
            kf[kc][nt] = *(const s16x8*)&kg[(size_t)((j0s) + nt * 16 + li) * DH_ + kc * 32 + g * 8]; \
    }
    #define LOADV(j0s)                                                         \
    {                                                                          \
        _Pragma("unroll")                                                      \
        for (int kc = 0; kc < 2; ++kc)                                         \
        _Pragma("unroll")                                                      \
        for (int dt = 0; dt < 4; ++dt)                                         \
            vf[kc][dt] = *(const s16x8*)&vtg[(size_t)(dt * 16 + li) * JT_ + (j0s) + kc * 32 + g * 8]; \
    }
    #define LOADB(j0s)                                                         \
    {                                                                          \
        _Pragma("unroll")                                                      \
        for (int nt = 0; nt < 4; ++nt)                                         \
            bnext[nt] = *(const f32x4*)&pb[(size_t)(qw + li) * JT_ + (j0s) + nt * 16 + g * 4]; \
    }

    LOADK(0);
    LOADV(0);
    LOADB(0);

    for (int t = 0; t < ntiles; ++t) {
        const int j0 = t * 64;
        const bool more = (t + 1 < ntiles);

        // S^T = mfma(K, Q) with bias as C-in (consumes bnext, kf of tile t)
        f32x4 sacc[4];
#pragma unroll
        for (int nt = 0; nt < 4; ++nt) sacc[nt] = bnext[nt];

        // prefetch bias for t+1 (window = full tile)
        if (more) LOADB(j0 + 64);

        __builtin_amdgcn_s_setprio(1);
#pragma unroll
        for (int kc = 0; kc < 2; ++kc)
#pragma unroll
            for (int nt = 0; nt < 4; ++nt)
                sacc[nt] = __builtin_amdgcn_mfma_f32_16x16x32_bf16(kf[kc][nt], aq[kc], sacc[nt], 0, 0, 0);
        __builtin_amdgcn_s_setprio(0);

        // prefetch K for t+1 right after consumption (window = softmax+PV)
        if (more) LOADK(j0 + 64);

        // ---- mask (diagonal tiles only, wave-uniform skip) ----
        const int q = qw + li;                 // this lane's q row
        if (j0 + 63 > MEM_ + qw) {
#pragma unroll
            for (int nt = 0; nt < 4; ++nt)
#pragma unroll
                for (int r = 0; r < 4; ++r) {
                    const int jg = j0 + nt * 16 + g * 4 + r;
                    if (jg > MEM_ + q) sacc[nt][r] = -1e30f;
                }
        }

        // ---- softmax: local max; defer-max (THR=8) skips reduce+rescale ----
        float t0 = fmaxf(fmaxf(sacc[0][0], sacc[0][1]), fmaxf(sacc[0][2], sacc[0][3]));
        float t1 = fmaxf(fmaxf(sacc[1][0], sacc[1][1]), fmaxf(sacc[1][2], sacc[1][3]));
        float t2 = fmaxf(fmaxf(sacc[2][0], sacc[2][1]), fmaxf(sacc[2][2], sacc[2][3]));
        float t3 = fmaxf(fmaxf(sacc[3][0], sacc[3][1]), fmaxf(sacc[3][2], sacc[3][3]));
        float tml = fmaxf(fmaxf(t0, t1), fmaxf(t2, t3));
        if (!__all(tml <= m_run + 8.0f)) {     // wave-uniform slow path
            float tm = tml;
            tm = fmaxf(tm, __shfl_xor(tm, 16));
            tm = fmaxf(tm, __shfl_xor(tm, 32));
            const float m_new = fmaxf(m_run, tm);
            const float sc = __expf(m_run - m_new);
            m_run = m_new;
            l_run *= sc;
#pragma unroll
            for (int dt = 0; dt < 4; ++dt) o[dt] *= sc;
        }

#pragma unroll
        for (int nt = 0; nt < 4; ++nt)
#pragma unroll
            for (int r = 0; r < 4; ++r)
                sacc[nt][r] = __expf(sacc[nt][r] - m_run);

        // per-lane partial sum (cross-group reduce deferred to epilogue)
        float s0 = (sacc[0][0] + sacc[0][1]) + (sacc[0][2] + sacc[0][3]);
        float s1 = (sacc[1][0] + sacc[1][1]) + (sacc[1][2] + sacc[1][3]);
        float s2 = (sacc[2][0] + sacc[2][1]) + (sacc[2][2] + sacc[2][3]);
        float s3 = (sacc[3][0] + sacc[3][1]) + (sacc[3][2] + sacc[3][3]);
        l_run += (s0 + s1) + (s2 + s3);

        // P store: [q=li][j = nt*16+g*4 .. +3] as b64, granule-swizzled
#pragma unroll
        for (int nt = 0; nt < 4; ++nt) {
            const int sl = nt * 4 + g;                  // 8B slot (col/4)
            const int gi = (sl >> 1) ^ (li & 7);        // 16B granule, XOR'd
            s16x4 pk;
            pk[0] = bf16_of(sacc[nt][0]);
            pk[1] = bf16_of(sacc[nt][1]);
            pk[2] = bf16_of(sacc[nt][2]);
            pk[3] = bf16_of(sacc[nt][3]);
            *(s16x4*)&P_lds[w][li * 64 + gi * 8 + (sl & 1) * 4] = pk;
        }

        // ---- O^T += mfma(A=V^T, B=P) (consumes vf of tile t) ----
        __builtin_amdgcn_s_setprio(1);
#pragma unroll
        for (int kc = 0; kc < 2; ++kc) {
            const int gir = (kc * 4 + g) ^ (li & 7);
            s16x8 pf = *(const s16x8*)&P_lds[w][li * 64 + gir * 8];
#pragma unroll
            for (int dt = 0; dt < 4; ++dt)
                o[dt] = __builtin_amdgcn_mfma_f32_16x16x32_bf16(vf[kc][dt], pf, o[dt], 0, 0, 0);
        }
        __builtin_amdgcn_s_setprio(0);

        // prefetch V for t+1 (window = next tile's QK + softmax)
        if (more) LOADV(j0 + 64);
    }
    #undef LOADK
    #undef LOADV
    #undef LOADB

    // ---- epilogue: reduce l across g-groups once, coalesced float4 stores ----
    {
        float ts = l_run;
        ts += __shfl_xor(ts, 16);
        ts += __shfl_xor(ts, 32);
        const float rinv = 1.0f / ts;
        const int q = qw + li;
#pragma unroll
        for (int dt = 0; dt < 4; ++dt) {
            f32x4 ov = o[dt] * rinv;
            *(f32x4*)&out[((size_t)(b * N_ + q)) * INNER_ + h * DH_ + dt * 16 + g * 4] = ov;
        }
    }
}

// ---------------------------------------------------------------------------
extern "C" void kernel_launch(void* const* d_in, const int* in_sizes, int n_in,
                              void* d_out, int out_size, void* d_ws, size_t ws_size,
                              hipStream_t stream)
{
    const float* x        = (const float*)d_in[0];
    const float* mem_k    = (const float*)d_in[1];
    const float* mem_v    = (const float*)d_in[2];
    const float* pos_bias = (const float*)d_in[3];
    const float* Wq       = (const float*)d_in[4];
    const float* Wkv      = (const float*)d_in[5];
    float* out = (float*)d_out;

    // workspace layout:
    //   qbuf  bf16  8 MiB   [b][h][i][64]
    //   kbuf  bf16 16 MiB   [b][h][j][64]
    //   vtbuf bf16 16 MiB   [b][h][d][j]
    //   xb    bf16  8 MiB   [4096][1024]
    //   Wt    bf16  6 MiB   [3072][1024]
    char* ws = (char*)d_ws;
    short* qbuf  = (short*)(ws);
    short* kbuf  = (short*)(ws + (8u << 20));
    short* vtbuf = (short*)(ws + (24u << 20));
    short* xb    = (short*)(ws + (40u << 20));
    short* Wt    = (short*)(ws + (48u << 20));

    cast_x<<<2048, 256, 0, stream>>>(x, xb);
    cast_w<<<dim3(16, 48), 256, 0, stream>>>(Wq, Wkv, Wt);
    prep_mem<<<dim3(32, H_, 4), 256, 0, stream>>>(mem_k, mem_v, kbuf, vtbuf);

    mfma_proj<<<dim3(24, 32), 256, 0, stream>>>(Wt, xb, qbuf, kbuf, vtbuf);

    attn_flash<<<1024, 256, 0, stream>>>(qbuf, kbuf, vtbuf, pos_bias, out);
}

// Round 16
// 226.682 us; speedup vs baseline: 2.1739x; 2.1739x over previous
//
#include <hip/hip_runtime.h>
#include <hip/hip_bf16.h>
#include <cstdint>

// Problem shapes (fixed)
#define B_     2
#define N_     2048
#define DIM_   1024
#define H_     16
#define DH_    64
#define MEM_   2048
#define JT_    4096      // MEM_ + N_
#define INNER_ 1024
#define SCALE_ 0.125f

typedef float f32x4 __attribute__((ext_vector_type(4)));
typedef short s16x8 __attribute__((ext_vector_type(8)));
typedef short s16x4 __attribute__((ext_vector_type(4)));

__device__ __forceinline__ short bf16_of(float f) {
    __hip_bfloat16 h = __float2bfloat16(f);   // RNE
    return *(short*)&h;
}

__device__ __forceinline__ void gload16(const void* g, short* l) {
    __builtin_amdgcn_global_load_lds(
        (const __attribute__((address_space(1))) unsigned int*)g,
        (__attribute__((address_space(3))) unsigned int*)l, 16, 0, 0);
}

// ---------------------------------------------------------------------------
// Kernel A: cast x fp32 [4096][1024] -> xb bf16 (row-major)
// ---------------------------------------------------------------------------
__global__ __launch_bounds__(256) void cast_x(
    const float* __restrict__ x, short* __restrict__ xb)
{
    const int total4 = B_ * N_ * DIM_ / 4;   // 1M
    for (int idx = blockIdx.x * blockDim.x + threadIdx.x; idx < total4;
         idx += gridDim.x * blockDim.x) {
        float4 v = ((const float4*)x)[idx];
        s16x4 o;
        o[0] = bf16_of(v.x); o[1] = bf16_of(v.y);
        o[2] = bf16_of(v.z); o[3] = bf16_of(v.w);
        *(s16x4*)&xb[idx * 4] = o;
    }
}

// ---------------------------------------------------------------------------
// Kernel B: transpose-cast weights -> Wt bf16 [3072][1024], Wt[n][k]=W[k][n].
// SCALE folded into q columns (n<1024).
// ---------------------------------------------------------------------------
__global__ __launch_bounds__(256) void cast_w(
    const float* __restrict__ Wq, const float* __restrict__ Wkv,
    short* __restrict__ Wt)
{
    const int kt = blockIdx.x;   // 0..15
    const int nt = blockIdx.y;   // 0..47
    __shared__ float tile[64][65];   // [n_local][k_local]
    const int t = threadIdx.x;
    const int r = t >> 2, s4 = (t & 3) * 16;

    const int n0 = nt * 64;
    const float* src;
    int ldn, nc0;
    if (n0 < 1024) { src = Wq;  ldn = 1024; nc0 = n0; }
    else           { src = Wkv; ldn = 2048; nc0 = n0 - 1024; }
    const float scale = (n0 < 1024) ? SCALE_ : 1.0f;

#pragma unroll
    for (int kq = 0; kq < 4; ++kq) {
        float4 v = *(const float4*)&src[(size_t)(kt * 64 + r) * ldn + nc0 + s4 + kq * 4];
        tile[s4 + kq * 4 + 0][r] = v.x;
        tile[s4 + kq * 4 + 1][r] = v.y;
        tile[s4 + kq * 4 + 2][r] = v.z;
        tile[s4 + kq * 4 + 3][r] = v.w;
    }
    __syncthreads();
    short ov[16];
#pragma unroll
    for (int e = 0; e < 16; ++e) ov[e] = bf16_of(tile[r][s4 + e] * scale);
    short* dst = &Wt[(size_t)(n0 + r) * 1024 + kt * 64 + s4];
    *(s16x8*)&dst[0] = *(s16x8*)&ov[0];
    *(s16x8*)&dst[8] = *(s16x8*)&ov[8];
}

// ---------------------------------------------------------------------------
// Kernel C: MFMA projection GEMM (unchanged from passing rounds 3-15).
// ---------------------------------------------------------------------------
#define PLDC 152

__global__ __launch_bounds__(256) void mfma_proj(
    const short* __restrict__ Wt, const short* __restrict__ xb,
    short* __restrict__ qbuf, short* __restrict__ kbuf, short* __restrict__ vtbuf)
{
    const int bc = blockIdx.x;
    const int bi = blockIdx.y;
    const int tid = threadIdx.x;
    const int w = tid >> 6, lane = tid & 63, g = lane >> 4, li = lane & 15;
    const int wr = w >> 1, wc = w & 1;

    __shared__ short smem[128 * PLDC];
    short* A_lds = smem;
    short* B_lds = smem + 8192;

    f32x4 acc[4][4];
#pragma unroll
    for (int m = 0; m < 4; ++m)
#pragma unroll
        for (int n = 0; n < 4; ++n) acc[m][n] = f32x4{0.f, 0.f, 0.f, 0.f};

    const size_t arow0 = (size_t)bc * 128;
    const size_t brow0 = (size_t)bi * 128;

    for (int t = 0; t < 16; ++t) {
        __syncthreads();
#pragma unroll
        for (int u = 0; u < 4; ++u) {
            const int c = (w * 4 + u) * 64 + lane;
            const int row = c >> 3, q = c & 7;
            const int qs = q ^ (row & 7);
            gload16(&Wt[(arow0 + row) * 1024 + t * 64 + qs * 8],
                    &A_lds[(w * 4 + u) * 512 + lane * 8]);
            gload16(&xb[(brow0 + row) * 1024 + t * 64 + qs * 8],
                    &B_lds[(w * 4 + u) * 512 + lane * 8]);
        }
        __syncthreads();
#pragma unroll
        for (int kc = 0; kc < 2; ++kc) {
            s16x8 af[4], bf[4];
#pragma unroll
            for (int mt = 0; mt < 4; ++mt) {
                const int row = wr * 64 + mt * 16 + li;
                af[mt] = *(const s16x8*)&A_lds[row * 64 + ((kc * 4 + g) ^ (row & 7)) * 8];
            }
#pragma unroll
            for (int nt = 0; nt < 4; ++nt) {
                const int row = wc * 64 + nt * 16 + li;
                bf[nt] = *(const s16x8*)&B_lds[row * 64 + ((kc * 4 + g) ^ (row & 7)) * 8];
            }
#pragma unroll
            for (int mt = 0; mt < 4; ++mt)
#pragma unroll
                for (int nt = 0; nt < 4; ++nt)
                    acc[mt][nt] = __builtin_amdgcn_mfma_f32_16x16x32_bf16(af[mt], bf[nt], acc[mt][nt], 0, 0, 0);
        }
    }

    __syncthreads();
    const int c0 = bc * 128;
    const int i0g = bi * 128;
    const int b = i0g >> 11;
    const int ii0 = i0g & 2047;

    if (c0 < 2048) {
#pragma unroll
        for (int mt = 0; mt < 4; ++mt)
#pragma unroll
            for (int nt = 0; nt < 4; ++nt) {
                const int i_l = wc * 64 + nt * 16 + li;
                const int c_l = wr * 64 + mt * 16 + g * 4;
                s16x4 v4;
                v4[0] = bf16_of(acc[mt][nt][0]);
                v4[1] = bf16_of(acc[mt][nt][1]);
                v4[2] = bf16_of(acc[mt][nt][2]);
                v4[3] = bf16_of(acc[mt][nt][3]);
                *(s16x4*)&smem[i_l * PLDC + c_l] = v4;
            }
        __syncthreads();
        const bool isq = (c0 < 1024);
#pragma unroll
        for (int u = 0; u < 8; ++u) {
            const int ch = tid + u * 256;
            const int i_l = ch >> 4, seg = ch & 15;
            s16x8 v = *(const s16x8*)&smem[i_l * PLDC + seg * 8];
            const int cg = c0 + seg * 8;
            const int h = (cg >> 6) & 15;
            const int d = cg & 63;
            if (isq)
                *(s16x8*)&qbuf[(((size_t)(b * H_ + h)) * N_ + ii0 + i_l) * DH_ + d] = v;
            else
                *(s16x8*)&kbuf[(((size_t)(b * H_ + h)) * JT_ + MEM_ + ii0 + i_l) * DH_ + d] = v;
        }
    } else {
#pragma unroll
        for (int mt = 0; mt < 4; ++mt)
#pragma unroll
            for (int nt = 0; nt < 4; ++nt) {
                const int i_l = wc * 64 + nt * 16 + li;
                const int c_b = wr * 64 + mt * 16 + g * 4;
#pragma unroll
                for (int r = 0; r < 4; ++r)
                    smem[(c_b + r) * PLDC + i_l] = bf16_of(acc[mt][nt][r]);
            }
        __syncthreads();
#pragma unroll
        for (int u = 0; u < 8; ++u) {
            const int ch = tid + u * 256;
            const int c_l = ch >> 4, seg = ch & 15;
            s16x8 v = *(const s16x8*)&smem[c_l * PLDC + seg * 8];
            const int cv = c0 + c_l - 2048;
            const int h = cv >> 6, d = cv & 63;
            *(s16x8*)&vtbuf[(((size_t)(b * H_ + h)) * DH_ + d) * JT_ + MEM_ + ii0 + seg * 8] = v;
        }
    }
}

// ---------------------------------------------------------------------------
// Kernel D (fused): mem_k copy-cast + mem_v transpose-cast, one launch.
// ---------------------------------------------------------------------------
__global__ __launch_bounds__(256) void prep_mem(
    const float* __restrict__ mem_k, const float* __restrict__ mem_v,
    short* __restrict__ kbuf, short* __restrict__ vtbuf)
{
    const int jt = blockIdx.x, h = blockIdx.y;
    const int b = blockIdx.z & 1, task = blockIdx.z >> 1;
    const int j0 = jt * 64;
    const int t = threadIdx.x;
    const int r = t >> 2, s4 = (t & 3) * 16;
    const size_t bh = (size_t)(b * H_ + h);

    if (task == 0) {
        short ov[16];
#pragma unroll
        for (int k = 0; k < 4; ++k) {
            float4 v = *(const float4*)&mem_k[((size_t)(b * MEM_ + j0 + r)) * INNER_ + h * DH_ + s4 + k * 4];
            ov[k * 4 + 0] = bf16_of(v.x);
            ov[k * 4 + 1] = bf16_of(v.y);
            ov[k * 4 + 2] = bf16_of(v.z);
            ov[k * 4 + 3] = bf16_of(v.w);
        }
        short* dst = &kbuf[(bh * JT_ + j0 + r) * DH_ + s4];
        *(s16x8*)&dst[0] = *(s16x8*)&ov[0];
        *(s16x8*)&dst[8] = *(s16x8*)&ov[8];
    } else {
        __shared__ float tile[64][65];
#pragma unroll
        for (int k = 0; k < 4; ++k) {
            float4 v = *(const float4*)&mem_v[((size_t)(b * MEM_ + j0 + r)) * INNER_ + h * DH_ + s4 + k * 4];
            tile[s4 + k * 4 + 0][r] = v.x;
            tile[s4 + k * 4 + 1][r] = v.y;
            tile[s4 + k * 4 + 2][r] = v.z;
            tile[s4 + k * 4 + 3][r] = v.w;
        }
        __syncthreads();
        short ov[16];
#pragma unroll
        for (int e = 0; e < 16; ++e) ov[e] = bf16_of(tile[r][s4 + e]);
        short* dst = &vtbuf[(bh * DH_ + r) * JT_ + j0 + s4];
        *(s16x8*)&dst[0] = *(s16x8*)&ov[0];
        *(s16x8*)&dst[8] = *(s16x8*)&ov[8];
    }
}

// ---------------------------------------------------------------------------
// Kernel F: flash attention (champion, r13): 64-key tiles, 1024 blocks x
// 4 waves x 16q, gload_lds K/V double-buffer (one __syncthreads per tile),
// XOR-swizzled source+read (rule #21 both-sides), swapped-operand softmax
// (lane-local 16 values + 2 shfl), defer-max THR=8, deferred l-reduction,
// bias as MFMA C-in prefetched 1 tile ahead, h%8 XCD grouping,
// complementary-zq pairing, granule-swizzled P (40 KB LDS, 4 blocks/CU).
// Measured 227.0 us total; r14 (fat waves) and r15 (barrier-free reg
// prefetch) both regressed -> this structure is the verified optimum.
// ---------------------------------------------------------------------------
__global__ __launch_bounds__(256, 4) void attn_flash(
    const short* __restrict__ qbuf, const short* __restrict__ kbuf,
    const short* __restrict__ vtbuf, const float* __restrict__ pos_bias,
    float* __restrict__ out)
{
    const int lid = blockIdx.x;                       // 0..1023
    const int h   = (lid & 7) | (((lid >> 3) & 1) << 3);   // h%8 = XCD
    const int b   = (lid >> 4) & 1;
    const int zql = (lid >> 5) & 15;
    const int hi  = lid >> 9;
    const int zq  = hi ? (31 - zql) : zql;            // balanced pairing
    const int i0  = zq * 64;                          // block's 64-query base

    const int tid = threadIdx.x;
    const int w = tid >> 6, lane = tid & 63, g = lane >> 4, li = lane & 15;

    __shared__ short K_lds[2][64 * 64];    // linear, chunk-swizzled content
    __shared__ short VT_lds[2][64 * 64];
    __shared__ short P_lds[4][16 * 64];    // swizzled pitch-64 (granule XOR)

    const size_t bh = (size_t)(b * H_ + h);
    const short* kg  = kbuf  + bh * (size_t)JT_ * DH_;
    const short* vtg = vtbuf + bh * (size_t)DH_ * JT_;
    const float* pb  = pos_bias + (size_t)h * N_ * JT_;

    const int qw = i0 + w * 16;            // wave's 16 q-rows

    // Q fragments (B operand of swapped QK^T): lane (g,li) holds Q[qw+li][k]
    s16x8 aq[2];
#pragma unroll
    for (int kc = 0; kc < 2; ++kc)
        aq[kc] = *(const s16x8*)&qbuf[(bh * N_ + qw + li) * DH_ + kc * 32 + g * 8];

    f32x4 o[4];
    float m_run = -3.0e38f, l_run = 0.f;   // l_run: PER-LANE partial sum
#pragma unroll
    for (int dt = 0; dt < 4; ++dt) o[dt] = f32x4{0.f, 0.f, 0.f, 0.f};

    const int ntiles = 33 + zq;   // covers j <= 2048 + i0 + 63

    // stage one 64-key tile: K 512 + VT 512 chunks of 16B over 256 threads
    #define STAGE(bufi, j0s)                                                   \
    {                                                                          \
        _Pragma("unroll")                                                      \
        for (int u = 0; u < 2; ++u) {                                          \
            const int c = u * 256 + tid;                                       \
            const int row = c >> 3, q = c & 7;                                 \
            const int qs = q ^ (row & 7);                                      \
            gload16(&kg[(size_t)((j0s) + row) * DH_ + qs * 8],                 \
                    &K_lds[bufi][c * 8]);                                      \
            gload16(&vtg[(size_t)row * JT_ + (j0s) + qs * 8],                  \
                    &VT_lds[bufi][c * 8]);                                     \
        }                                                                      \
    }

    // bias prefetch: lane (g,li) holds bias[q=qw+li][j0+nt*16+g*4 .. +3]
    f32x4 bnext[4];
    #define LOADB(j0s)                                                         \
    {                                                                          \
        _Pragma("unroll")                                                      \
        for (int nt = 0; nt < 4; ++nt)                                         \
            bnext[nt] = *(const f32x4*)&pb[(size_t)(qw + li) * JT_ + (j0s) + nt * 16 + g * 4]; \
    }

    STAGE(0, 0);
    LOADB(0);
    __syncthreads();   // drains vmcnt: tile 0 staged, bias(0) in regs

    for (int t = 0; t < ntiles; ++t) {
        const int cur = t & 1;
        const int j0 = t * 64;
        const bool more = (t + 1 < ntiles);

        // issue next tile's staging BEFORE compute (hidden under this tile)
        if (more) STAGE(cur ^ 1, j0 + 64);

        // S^T = mfma(K, Q) with bias as C-in
        f32x4 sacc[4];
#pragma unroll
        for (int nt = 0; nt < 4; ++nt) sacc[nt] = bnext[nt];

        // prefetch bias for tile t+1 (consumed after next barrier)
        if (more) LOADB(j0 + 64);

        __builtin_amdgcn_s_setprio(1);
#pragma unroll
        for (int kc = 0; kc < 2; ++kc)
#pragma unroll
            for (int nt = 0; nt < 4; ++nt) {
                s16x8 bk = *(const s16x8*)&K_lds[cur][(nt * 16 + li) * 64 + ((kc * 4 + g) ^ (li & 7)) * 8];
                sacc[nt] = __builtin_amdgcn_mfma_f32_16x16x32_bf16(bk, aq[kc], sacc[nt], 0, 0, 0);
            }
        __builtin_amdgcn_s_setprio(0);

        // ---- mask (diagonal tiles only, wave-uniform skip) ----
        const int q = qw + li;                 // this lane's q row
        if (j0 + 63 > MEM_ + qw) {
#pragma unroll
            for (int nt = 0; nt < 4; ++nt)
#pragma unroll
                for (int r = 0; r < 4; ++r) {
                    const int jg = j0 + nt * 16 + g * 4 + r;
                    if (jg > MEM_ + q) sacc[nt][r] = -1e30f;
                }
        }

        // ---- softmax: local max; defer-max (THR=8) skips reduce+rescale ----
        float t0 = fmaxf(fmaxf(sacc[0][0], sacc[0][1]), fmaxf(sacc[0][2], sacc[0][3]));
        float t1 = fmaxf(fmaxf(sacc[1][0], sacc[1][1]), fmaxf(sacc[1][2], sacc[1][3]));
        float t2 = fmaxf(fmaxf(sacc[2][0], sacc[2][1]), fmaxf(sacc[2][2], sacc[2][3]));
        float t3 = fmaxf(fmaxf(sacc[3][0], sacc[3][1]), fmaxf(sacc[3][2], sacc[3][3]));
        float tml = fmaxf(fmaxf(t0, t1), fmaxf(t2, t3));
        if (!__all(tml <= m_run + 8.0f)) {     // wave-uniform slow path
            float tm = tml;
            tm = fmaxf(tm, __shfl_xor(tm, 16));
            tm = fmaxf(tm, __shfl_xor(tm, 32));
            const float m_new = fmaxf(m_run, tm);
            const float sc = __expf(m_run - m_new);
            m_run = m_new;
            l_run *= sc;
#pragma unroll
            for (int dt = 0; dt < 4; ++dt) o[dt] *= sc;
        }

#pragma unroll
        for (int nt = 0; nt < 4; ++nt)
#pragma unroll
            for (int r = 0; r < 4; ++r)
                sacc[nt][r] = __expf(sacc[nt][r] - m_run);

        // per-lane partial sum (cross-group reduce deferred to epilogue)
        float s0 = (sacc[0][0] + sacc[0][1]) + (sacc[0][2] + sacc[0][3]);
        float s1 = (sacc[1][0] + sacc[1][1]) + (sacc[1][2] + sacc[1][3]);
        float s2 = (sacc[2][0] + sacc[2][1]) + (sacc[2][2] + sacc[2][3]);
        float s3 = (sacc[3][0] + sacc[3][1]) + (sacc[3][2] + sacc[3][3]);
        l_run += (s0 + s1) + (s2 + s3);

        // P store: [q=li][j = nt*16+g*4 .. +3] as b64, granule-swizzled
#pragma unroll
        for (int nt = 0; nt < 4; ++nt) {
            const int sl = nt * 4 + g;                  // 8B slot (col/4)
            const int gi = (sl >> 1) ^ (li & 7);        // 16B granule, XOR'd
            s16x4 pk;
            pk[0] = bf16_of(sacc[nt][0]);
            pk[1] = bf16_of(sacc[nt][1]);
            pk[2] = bf16_of(sacc[nt][2]);
            pk[3] = bf16_of(sacc[nt][3]);
            *(s16x4*)&P_lds[w][li * 64 + gi * 8 + (sl & 1) * 4] = pk;
        }

        // ---- O^T += mfma(A=V^T, B=P) ----
        __builtin_amdgcn_s_setprio(1);
#pragma unroll
        for (int kc = 0; kc < 2; ++kc) {
            const int gir = (kc * 4 + g) ^ (li & 7);
            s16x8 pf = *(const s16x8*)&P_lds[w][li * 64 + gir * 8];
#pragma unroll
            for (int dt = 0; dt < 4; ++dt) {
                s16x8 bv = *(const s16x8*)&VT_lds[cur][(dt * 16 + li) * 64 + ((kc * 4 + g) ^ (li & 7)) * 8];
                o[dt] = __builtin_amdgcn_mfma_f32_16x16x32_bf16(bv, pf, o[dt], 0, 0, 0);
            }
        }
        __builtin_amdgcn_s_setprio(0);

        __syncthreads();   // drains vmcnt (tile t+1 staged); all reads of cur done
    }
    #undef STAGE
    #undef LOADB

    // ---- epilogue: reduce l across g-groups once, then coalesced stores ----
    {
        float ts = l_run;
        ts += __shfl_xor(ts, 16);
        ts += __shfl_xor(ts, 32);
        const float rinv = 1.0f / ts;
        const int q = qw + li;
#pragma unroll
        for (int dt = 0; dt < 4; ++dt) {
            f32x4 ov = o[dt] * rinv;
            *(f32x4*)&out[((size_t)(b * N_ + q)) * INNER_ + h * DH_ + dt * 16 + g * 4] = ov;
        }
    }
}

// ---------------------------------------------------------------------------
extern "C" void kernel_launch(void* const* d_in, const int* in_sizes, int n_in,
                              void* d_out, int out_size, void* d_ws, size_t ws_size,
                              hipStream_t stream)
{
    const float* x        = (const float*)d_in[0];
    const float* mem_k    = (const float*)d_in[1];
    const float* mem_v    = (const float*)d_in[2];
    const float* pos_bias = (const float*)d_in[3];
    const float* Wq       = (const float*)d_in[4];
    const float* Wkv      = (const float*)d_in[5];
    float* out = (float*)d_out;

    // workspace layout:
    //   qbuf  bf16  8 MiB   [b][h][i][64]
    //   kbuf  bf16 16 MiB   [b][h][j][64]
    //   vtbuf bf16 16 MiB   [b][h][d][j]
    //   xb    bf16  8 MiB   [4096][1024]
    //   Wt    bf16  6 MiB   [3072][1024]
    char* ws = (char*)d_ws;
    short* qbuf  = (short*)(ws);
    short* kbuf  = (short*)(ws + (8u << 20));
    short* vtbuf = (short*)(ws + (24u << 20));
    short* xb    = (short*)(ws + (40u << 20));
    short* Wt    = (short*)(ws + (48u << 20));

    cast_x<<<2048, 256, 0, stream>>>(x, xb);
    cast_w<<<dim3(16, 48), 256, 0, stream>>>(Wq, Wkv, Wt);
    prep_mem<<<dim3(32, H_, 4), 256, 0, stream>>>(mem_k, mem_v, kbuf, vtbuf);

    mfma_proj<<<dim3(24, 32), 256, 0, stream>>>(Wt, xb, qbuf, kbuf, vtbuf);

    attn_flash<<<1024, 256, 0, stream>>>(qbuf, kbuf, vtbuf, pos_bias, out);
}